// Round 3
// baseline (923.473 us; speedup 1.0000x reference)
//
#include <hip/hip_runtime.h>

constexpr int N_NODES = 50000;
constexpr int E_EDGES = 1600000;
constexpr int NH      = N_NODES * 32;   // 1,600,000
constexpr float BN_EPS = 1e-5f;
constexpr int NPAD    = 50016;
constexpr int GBLK    = N_NODES / 8;    // 6250 gather blocks, 64 partials each

// ---------------------------------------------------------------- zero scratch
__global__ void zero_kernel(float4* __restrict__ p, int n4) {
    int i = blockIdx.x * blockDim.x + threadIdx.x;
    if (i < n4) p[i] = make_float4(0.f, 0.f, 0.f, 0.f);
}

// ---------------------------------------------------------------- CSR build
// 2 edges per thread: int2 loads halve issue/address overhead around atomics
__global__ void hist_kernel(const int* __restrict__ ei, int* __restrict__ counts) {
    int t = blockIdx.x * blockDim.x + threadIdx.x;
    if (t < E_EDGES / 2) {
        int2 d = ((const int2*)(ei + E_EDGES))[t];
        atomicAdd(&counts[d.x], 1);
        atomicAdd(&counts[d.y], 1);
    }
}

__device__ inline int block_excl_scan(int v, int* s) {
    int t = threadIdx.x;
    s[t] = v;
    __syncthreads();
    for (int d = 1; d < 256; d <<= 1) {
        int x = (t >= d) ? s[t - d] : 0;
        __syncthreads();
        s[t] += x;
        __syncthreads();
    }
    return s[t] - v;   // exclusive
}

__global__ void scan1_kernel(const int* __restrict__ counts, int* __restrict__ bsum) {
    int i = blockIdx.x * 256 + threadIdx.x;
    int v = (i < N_NODES) ? counts[i] : 0;
#pragma unroll
    for (int o = 32; o > 0; o >>= 1) v += __shfl_down(v, o);
    __shared__ int s[4];
    int wave = threadIdx.x >> 6, lane = threadIdx.x & 63;
    if (lane == 0) s[wave] = v;
    __syncthreads();
    if (threadIdx.x == 0) bsum[blockIdx.x] = s[0] + s[1] + s[2] + s[3];
}

// merged scan2+scan3: every block redundantly scans the 196 block sums in LDS
// (196 ints -- cheaper than a separate 1-block kernel launch + its GPU-wide idle)
__global__ void scan23_kernel(const int* __restrict__ counts, const int* __restrict__ bsum,
                              int* __restrict__ off, int* __restrict__ cursor) {
    __shared__ int s[256], s2[256], sb[256];
    int t = threadIdx.x;
    int bv = (t < 196) ? bsum[t] : 0;
    int bexcl = block_excl_scan(bv, s2);
    sb[t] = bexcl;
    __syncthreads();
    int blockoff = sb[blockIdx.x];

    int i = blockIdx.x * 256 + t;
    int v = (i < N_NODES) ? counts[i] : 0;
    int excl = block_excl_scan(v, s) + blockoff;
    if (i < N_NODES) { off[i] = excl; cursor[i] = excl; }
    if (i == N_NODES - 1) off[N_NODES] = excl + v;   // == E
}

// one interleaved int2 {tagged_src, w_bits} per edge; 2 edges per thread
__global__ void place_kernel(const int* __restrict__ ei, const float* __restrict__ ew,
                             int* __restrict__ cursor, int2* __restrict__ ep) {
    int t = blockIdx.x * blockDim.x + threadIdx.x;
    if (t < E_EDGES / 2) {
        int2   sp = ((const int2*)ei)[t];
        int2   dp = ((const int2*)(ei + E_EDGES))[t];
        float2 wp = ((const float2*)ew)[t];
        int pos0 = atomicAdd(&cursor[dp.x], 1);
        ep[pos0] = make_int2(sp.x | ((sp.x == dp.x) ? 0x80000000 : 0),
                             __float_as_int(wp.x));
        int pos1 = atomicAdd(&cursor[dp.y], 1);
        ep[pos1] = make_int2(sp.y | ((sp.y == dp.y) ? 0x80000000 : 0),
                             __float_as_int(wp.y));
    }
}

// ---------------------------------------------------------------- fused gather + fc1:
// BN + weighted neighbor sum + 32x32 W-contraction + relu + fc1 row-dot.
// ONE WAVE PER 2 NODES (full 6250-block TLP -- round-1 lesson: never cut
// parallelism for fusion). After a node's 32 relu'd outputs are staged in LDS,
// lane j dots them with fc1_w[j, n*32..n*32+31] (one 128B line per lane per
// node, fully consumed -> 100% DRAM efficiency). The 409.6 MB fc1_w stream
// hides under gather latency; rres never touches HBM; fc1 launch deleted.
__global__ void gather_fc1_kernel(const float* __restrict__ x,
                                  const float* __restrict__ gamma,
                                  const float* __restrict__ beta,
                                  const float* __restrict__ mean,
                                  const float* __restrict__ var,
                                  const int*   __restrict__ off,
                                  const int2*  __restrict__ ep,
                                  const float* __restrict__ W,
                                  const float* __restrict__ fc1_w,
                                  float* __restrict__ partial) {
    __shared__ float2 s_wp[1024];            // {Wsum, W0} packed per (cc, h)
    __shared__ float  s_ap[4][64];           // per-wave {acc, acc0} interleaved
    __shared__ float4 s_rr[4][8];            // per-wave relu'd node result (32 f)
    __shared__ float  s_red[256];            // block fc1 partial reduce
    int tid = threadIdx.x;
    for (int idx = tid; idx < 1024; idx += 256)
        s_wp[idx] = make_float2(W[1024 + idx] + W[2048 + idx], W[idx]);
    __syncthreads();

    int lane  = tid & 63;
    int c     = lane & 31;                   // channel
    int half  = lane >> 5;                   // which edge of the pair
    int wslot = tid >> 6;                    // wave slot in block
    int wid   = (blockIdx.x << 2) + wslot;   // global wave id, 0..24999

    float sc = gamma[c] * rsqrtf(var[c] + BN_EPS);
    float sh = beta[c] - mean[c] * sc;

    const float2* ap2  = (const float2*)s_ap[wslot];
    const float*  wrow = fc1_w + (size_t)lane * NH;   // this lane's fc1 row
    float facc = 0.f;                                  // fc1 partial for row `lane`

#pragma unroll
    for (int i = 0; i < 2; i++) {            // 2 nodes per wave
        int n  = (wid << 1) + i;
        int e0 = off[n];
        int nb = off[n + 1] - e0;
        const int2* e2 = ep + e0;

        float acc = 0.f, acc0 = 0.f;
        int base = 0;
        for (; base + 8 <= nb; base += 8) {          // 4 pair-chunks in flight
#pragma unroll
            for (int k = 0; k < 4; k++) {
                int2 p = e2[base + (k << 1) + half]; // broadcast within half
                float vv = fmaf(x[(p.x & 0x7fffffff) * 32 + c], sc, sh);
                acc = fmaf(__int_as_float(p.y), vv, acc);
                if (p.x < 0) acc0 += vv;
            }
        }
        for (; base + 2 <= nb; base += 2) {          // pair tail
            int2 p = e2[base + half];
            float vv = fmaf(x[(p.x & 0x7fffffff) * 32 + c], sc, sh);
            acc = fmaf(__int_as_float(p.y), vv, acc);
            if (p.x < 0) acc0 += vv;
        }
        if (base < nb && half == 0) {                // odd edge: half 0 only
            int2 p = e2[base];
            float vv = fmaf(x[(p.x & 0x7fffffff) * 32 + c], sc, sh);
            acc = fmaf(__int_as_float(p.y), vv, acc);
            if (p.x < 0) acc0 += vv;
        }

        // combine halves -> both halves hold full acc/acc0 per channel c
        acc  += __shfl_xor(acc,  32);
        acc0 += __shfl_xor(acc0, 32);

        // stage {acc, acc0} interleaved; wave-private slot, no __syncthreads
        __builtin_amdgcn_wave_barrier();
        s_ap[wslot][(c << 1) | half] = half ? acc0 : acc;
        __threadfence_block();                       // drain ds_write (lgkmcnt)
        __builtin_amdgcn_wave_barrier();

        // contraction: half 0 sums cc=0..15, half 1 sums cc=16..31
        float r = 0.f;
        int ccb = half << 4;
#pragma unroll
        for (int t = 0; t < 16; t++) {
            int cc = ccb + t;
            float2 ap = ap2[cc];                     // broadcast per half
            float2 wp = s_wp[cc * 32 + c];
            r = fmaf(ap.x, wp.x, r);
            r = fmaf(ap.y, wp.y, r);
        }
        r += __shfl_xor(r, 32);                      // full result, both halves

        // stage relu'd node result for the fc1 dot
        __builtin_amdgcn_wave_barrier();
        if (half == 0) ((float*)s_rr[wslot])[c] = fmaxf(r, 0.f);
        __threadfence_block();
        __builtin_amdgcn_wave_barrier();

        // fc1: lane j accumulates <rres[n,:], fc1_w[j, n*32:(n+1)*32]>
        const float4* wp4 = (const float4*)(wrow + ((size_t)n << 5));
#pragma unroll
        for (int q = 0; q < 8; q++) {
            float4 wv = wp4[q];                      // 128B line, lane-private
            float4 rv = s_rr[wslot][q];              // broadcast to all 64 lanes
            facc = fmaf(rv.x, wv.x, facc);
            facc = fmaf(rv.y, wv.y, facc);
            facc = fmaf(rv.z, wv.z, facc);
            facc = fmaf(rv.w, wv.w, facc);
        }
        __builtin_amdgcn_wave_barrier();
    }

    // block-level reduce: 4 waves x 64 rows -> partial[block][64]
    s_red[(wslot << 6) + lane] = facc;
    __syncthreads();
    if (wslot == 0)
        partial[blockIdx.x * 64 + lane] =
            s_red[lane] + s_red[64 + lane] + s_red[128 + lane] + s_red[192 + lane];
}

// ---------------------------------------------------------------- reduce + head
__global__ void reduce_head_kernel(const float* __restrict__ partial,
                                   const float* __restrict__ fc1_b,
                                   const float* __restrict__ fc2_w,
                                   const float* __restrict__ fc2_b,
                                   float* __restrict__ out) {
    __shared__ float red[1024];
    int t = threadIdx.x;
    int j = t & 63, s = t >> 6;          // 16 slices over 6250 blocks
    float a = 0.f;
    for (int b = s; b < GBLK; b += 16) a += partial[b * 64 + j];  // coalesced
    red[t] = a;
    __syncthreads();
    if (s == 0) {
        float h = fc1_b[j];
#pragma unroll
        for (int q = 0; q < 16; q++) h += red[q * 64 + j];
        h = fmaxf(h, 0.f);
#pragma unroll
        for (int k = 0; k < 2; k++) {
            float p = h * fc2_w[k * 64 + j];
#pragma unroll
            for (int o = 32; o > 0; o >>= 1) p += __shfl_down(p, o);
            if (j == 0) out[k] = p + fc2_b[k];
        }
    }
}

// ---------------------------------------------------------------- launch
extern "C" void kernel_launch(void* const* d_in, const int* in_sizes, int n_in,
                              void* d_out, int out_size, void* d_ws, size_t ws_size,
                              hipStream_t stream) {
    const float* x     = (const float*)d_in[0];
    const float* ew    = (const float*)d_in[1];
    const float* W     = (const float*)d_in[2];
    const float* gamma = (const float*)d_in[3];
    const float* beta  = (const float*)d_in[4];
    const float* mean  = (const float*)d_in[5];
    const float* var   = (const float*)d_in[6];
    const float* fc1_w = (const float*)d_in[7];
    const float* fc1_b = (const float*)d_in[8];
    const float* fc2_w = (const float*)d_in[9];
    const float* fc2_b = (const float*)d_in[10];
    const int*   ei    = (const int*)d_in[11];
    float* out = (float*)d_out;

    // ws layout (4B elems): partial(GBLK*64=400000) | counts(NPAD) | off(NPAD)
    //   | cursor(NPAD) | bsum(256) | ep(int2 x E)            ~ 14.6 MB
    float* partial = (float*)d_ws;
    int*   counts  = (int*)d_ws + GBLK * 64;
    int*   off     = counts + NPAD;
    int*   cursor  = off + NPAD;
    int*   bsum    = cursor + NPAD;
    int2*  ep      = (int2*)(bsum + 256);       // 8B-aligned
    (void)ws_size; (void)in_sizes; (void)n_in; (void)out_size;

    {   // zero counts only (partial fully overwritten every call)
        int n4 = NPAD / 4;
        zero_kernel<<<(n4 + 255) / 256, 256, 0, stream>>>((float4*)counts, n4);
    }
    hist_kernel  <<<(E_EDGES / 2 + 255) / 256, 256, 0, stream>>>(ei, counts);
    scan1_kernel <<<196, 256, 0, stream>>>(counts, bsum);
    scan23_kernel<<<196, 256, 0, stream>>>(counts, bsum, off, cursor);
    place_kernel <<<(E_EDGES / 2 + 255) / 256, 256, 0, stream>>>(ei, ew, cursor, ep);
    gather_fc1_kernel<<<GBLK, 256, 0, stream>>>(x, gamma, beta, mean, var,
                                                off, ep, W, fc1_w, partial);
    reduce_head_kernel<<<1, 1024, 0, stream>>>(partial, fc1_b, fc2_w, fc2_b, out);
}

// Round 4
// 822.702 us; speedup vs baseline: 1.1225x; 1.1225x over previous
//
#include <hip/hip_runtime.h>

constexpr int N_NODES = 50000;
constexpr int E_EDGES = 1600000;
constexpr int NH      = N_NODES * 32;   // 1,600,000
constexpr float BN_EPS = 1e-5f;
constexpr int NPAD    = 50016;
constexpr int NBLK    = 1250;           // fc1 chunk blocks

// ---------------------------------------------------------------- zero scratch
__global__ void zero_kernel(float4* __restrict__ p, int n4) {
    int i = blockIdx.x * blockDim.x + threadIdx.x;
    if (i < n4) p[i] = make_float4(0.f, 0.f, 0.f, 0.f);
}

// ---------------------------------------------------------------- CSR build
// 2 edges per thread: int2 loads halve issue/address overhead around atomics
__global__ void hist_kernel(const int* __restrict__ ei, int* __restrict__ counts) {
    int t = blockIdx.x * blockDim.x + threadIdx.x;
    if (t < E_EDGES / 2) {
        int2 d = ((const int2*)(ei + E_EDGES))[t];
        atomicAdd(&counts[d.x], 1);
        atomicAdd(&counts[d.y], 1);
    }
}

__device__ inline int block_excl_scan(int v, int* s) {
    int t = threadIdx.x;
    s[t] = v;
    __syncthreads();
    for (int d = 1; d < 256; d <<= 1) {
        int x = (t >= d) ? s[t - d] : 0;
        __syncthreads();
        s[t] += x;
        __syncthreads();
    }
    return s[t] - v;   // exclusive
}

__global__ void scan1_kernel(const int* __restrict__ counts, int* __restrict__ bsum) {
    int i = blockIdx.x * 256 + threadIdx.x;
    int v = (i < N_NODES) ? counts[i] : 0;
#pragma unroll
    for (int o = 32; o > 0; o >>= 1) v += __shfl_down(v, o);
    __shared__ int s[4];
    int wave = threadIdx.x >> 6, lane = threadIdx.x & 63;
    if (lane == 0) s[wave] = v;
    __syncthreads();
    if (threadIdx.x == 0) bsum[blockIdx.x] = s[0] + s[1] + s[2] + s[3];
}

// merged scan2+scan3: every block redundantly scans the 196 block sums in LDS
__global__ void scan23_kernel(const int* __restrict__ counts, const int* __restrict__ bsum,
                              int* __restrict__ off, int* __restrict__ cursor) {
    __shared__ int s[256], s2[256], sb[256];
    int t = threadIdx.x;
    int bv = (t < 196) ? bsum[t] : 0;
    int bexcl = block_excl_scan(bv, s2);
    sb[t] = bexcl;
    __syncthreads();
    int blockoff = sb[blockIdx.x];

    int i = blockIdx.x * 256 + t;
    int v = (i < N_NODES) ? counts[i] : 0;
    int excl = block_excl_scan(v, s) + blockoff;
    if (i < N_NODES) { off[i] = excl; cursor[i] = excl; }
    if (i == N_NODES - 1) off[N_NODES] = excl + v;   // == E
}

// one interleaved int2 {tagged_src, w_bits} per edge; 2 edges per thread
__global__ void place_kernel(const int* __restrict__ ei, const float* __restrict__ ew,
                             int* __restrict__ cursor, int2* __restrict__ ep) {
    int t = blockIdx.x * blockDim.x + threadIdx.x;
    if (t < E_EDGES / 2) {
        int2   sp = ((const int2*)ei)[t];
        int2   dp = ((const int2*)(ei + E_EDGES))[t];
        float2 wp = ((const float2*)ew)[t];
        int pos0 = atomicAdd(&cursor[dp.x], 1);
        ep[pos0] = make_int2(sp.x | ((sp.x == dp.x) ? 0x80000000 : 0),
                             __float_as_int(wp.x));
        int pos1 = atomicAdd(&cursor[dp.y], 1);
        ep[pos1] = make_int2(sp.y | ((sp.y == dp.y) ? 0x80000000 : 0),
                             __float_as_int(wp.y));
    }
}

// ---------------------------------------------------------------- fused gather:
// BN + weighted neighbor sum + 32x32 W-contraction + relu.
// ONE WAVE PER NODE: 64 lanes = 2 edges x 32 channels; nb wave-uniform,
// edge records via broadcast int2 loads. Round-4 change: 16-edge chunks
// (8 loads in flight per half) to double MLP in the latency-bound edge loop.
__global__ void gather_kernel(const float* __restrict__ x,
                              const float* __restrict__ gamma,
                              const float* __restrict__ beta,
                              const float* __restrict__ mean,
                              const float* __restrict__ var,
                              const int*   __restrict__ off,
                              const int2*  __restrict__ ep,
                              const float* __restrict__ W,
                              float* __restrict__ rres) {
    __shared__ float2 s_wp[1024];            // {Wsum, W0} packed per (cc, h)
    __shared__ float  s_ap[4][64];           // per-wave {acc, acc0} interleaved
    int tid = threadIdx.x;
    for (int idx = tid; idx < 1024; idx += 256)
        s_wp[idx] = make_float2(W[1024 + idx] + W[2048 + idx], W[idx]);
    __syncthreads();

    int lane  = tid & 63;
    int c     = lane & 31;                   // channel
    int half  = lane >> 5;                   // which edge of the pair
    int wslot = tid >> 6;                    // wave slot in block
    int wid   = (blockIdx.x << 2) + wslot;   // global wave id, 0..24999

    float sc = gamma[c] * rsqrtf(var[c] + BN_EPS);
    float sh = beta[c] - mean[c] * sc;

    const float2* ap2 = (const float2*)s_ap[wslot];

#pragma unroll
    for (int i = 0; i < 2; i++) {            // 2 nodes per wave
        int n  = (wid << 1) + i;
        int e0 = off[n];
        int nb = off[n + 1] - e0;
        const int2* e2 = ep + e0;

        float acc = 0.f, acc0 = 0.f;
        int base = 0;
        for (; base + 16 <= nb; base += 16) {        // 8 pair-chunks in flight
            int2 p[8];
#pragma unroll
            for (int k = 0; k < 8; k++) p[k] = e2[base + (k << 1) + half];
#pragma unroll
            for (int k = 0; k < 8; k++) {
                float vv = fmaf(x[(p[k].x & 0x7fffffff) * 32 + c], sc, sh);
                acc = fmaf(__int_as_float(p[k].y), vv, acc);
                if (p[k].x < 0) acc0 += vv;
            }
        }
        if (base + 8 <= nb) {                        // 4 pair-chunks
            int2 p[4];
#pragma unroll
            for (int k = 0; k < 4; k++) p[k] = e2[base + (k << 1) + half];
#pragma unroll
            for (int k = 0; k < 4; k++) {
                float vv = fmaf(x[(p[k].x & 0x7fffffff) * 32 + c], sc, sh);
                acc = fmaf(__int_as_float(p[k].y), vv, acc);
                if (p[k].x < 0) acc0 += vv;
            }
            base += 8;
        }
        for (; base + 2 <= nb; base += 2) {          // pair tail
            int2 p = e2[base + half];
            float vv = fmaf(x[(p.x & 0x7fffffff) * 32 + c], sc, sh);
            acc = fmaf(__int_as_float(p.y), vv, acc);
            if (p.x < 0) acc0 += vv;
        }
        if (base < nb && half == 0) {                // odd edge: half 0 only
            int2 p = e2[base];
            float vv = fmaf(x[(p.x & 0x7fffffff) * 32 + c], sc, sh);
            acc = fmaf(__int_as_float(p.y), vv, acc);
            if (p.x < 0) acc0 += vv;
        }

        // combine halves -> both halves hold full acc/acc0 per channel c
        acc  += __shfl_xor(acc,  32);
        acc0 += __shfl_xor(acc0, 32);

        // stage {acc, acc0} interleaved; wave-private slot, no __syncthreads
        __builtin_amdgcn_wave_barrier();
        s_ap[wslot][(c << 1) | half] = half ? acc0 : acc;
        __threadfence_block();                       // drain ds_write (lgkmcnt)
        __builtin_amdgcn_wave_barrier();

        // contraction: half 0 sums cc=0..15, half 1 sums cc=16..31
        float r = 0.f;
        int ccb = half << 4;
#pragma unroll
        for (int t = 0; t < 16; t++) {
            int cc = ccb + t;
            float2 ap = ap2[cc];                     // broadcast per half
            float2 wp = s_wp[cc * 32 + c];
            r = fmaf(ap.x, wp.x, r);
            r = fmaf(ap.y, wp.y, r);
        }
        r += __shfl_xor(r, 32);
        if (half == 0) rres[n * 32 + c] = fmaxf(r, 0.f);
        __builtin_amdgcn_wave_barrier();
    }
}

// ---------------------------------------------------------------- fc1: [1,NH] @ [NH,64]^T
// 1250 blocks (CHUNK=1280): halves tail quantization vs 625 on the chain's
// largest necessary HBM stream. 4 waves, 16 rows/wave, LDS r-stage,
// atomic-free per-block partials. Coalesced: wave reads 64 consecutive
// float4 = 1KB burst per instruction (the pattern round-3's fusion broke).
constexpr int CHUNK = 1280;   // 320 float4; NH/CHUNK = 1250
__global__ void fc1_kernel(const float* __restrict__ r,
                           const float* __restrict__ w,
                           float* __restrict__ partial) {
    __shared__ float4 s_r[320];
    int tid = threadIdx.x;
    size_t ib = (size_t)blockIdx.x * CHUNK;
    const float4* r4 = (const float4*)(r + ib);
    for (int i = tid; i < 320; i += 256) s_r[i] = r4[i];
    __syncthreads();

    int wave = tid >> 6, lane = tid & 63;
    int jbase = wave * 16;
    float* pout = partial + blockIdx.x * 64;
    for (int jj = 0; jj < 16; jj += 2) {
        const float4* wa = (const float4*)(w + (size_t)(jbase + jj    ) * NH + ib);
        const float4* wb = (const float4*)(w + (size_t)(jbase + jj + 1) * NH + ib);
        float a0 = 0.f, a1 = 0.f;
#pragma unroll
        for (int k = 0; k < 5; k++) {
            float4 rv = s_r[lane + k * 64];
            float4 x0 = wa[lane + k * 64];
            float4 x1 = wb[lane + k * 64];
            a0 = fmaf(rv.x, x0.x, a0); a0 = fmaf(rv.y, x0.y, a0);
            a0 = fmaf(rv.z, x0.z, a0); a0 = fmaf(rv.w, x0.w, a0);
            a1 = fmaf(rv.x, x1.x, a1); a1 = fmaf(rv.y, x1.y, a1);
            a1 = fmaf(rv.z, x1.z, a1); a1 = fmaf(rv.w, x1.w, a1);
        }
#pragma unroll
        for (int o = 32; o > 0; o >>= 1) {
            a0 += __shfl_down(a0, o);
            a1 += __shfl_down(a1, o);
        }
        if (lane == 0) {
            pout[jbase + jj    ] = a0;   // plain store, distinct address per block
            pout[jbase + jj + 1] = a1;
        }
    }
}

// ---------------------------------------------------------------- reduce + head
__global__ void reduce_head_kernel(const float* __restrict__ partial,
                                   const float* __restrict__ fc1_b,
                                   const float* __restrict__ fc2_w,
                                   const float* __restrict__ fc2_b,
                                   float* __restrict__ out) {
    __shared__ float red[1024];
    int t = threadIdx.x;
    int j = t & 63, s = t >> 6;          // 16 slices over 1250 blocks
    float a = 0.f;
    for (int b = s; b < NBLK; b += 16) a += partial[b * 64 + j];  // coalesced
    red[t] = a;
    __syncthreads();
    if (s == 0) {
        float h = fc1_b[j];
#pragma unroll
        for (int q = 0; q < 16; q++) h += red[q * 64 + j];
        h = fmaxf(h, 0.f);
#pragma unroll
        for (int k = 0; k < 2; k++) {
            float p = h * fc2_w[k * 64 + j];
#pragma unroll
            for (int o = 32; o > 0; o >>= 1) p += __shfl_down(p, o);
            if (j == 0) out[k] = p + fc2_b[k];
        }
    }
}

// ---------------------------------------------------------------- launch
extern "C" void kernel_launch(void* const* d_in, const int* in_sizes, int n_in,
                              void* d_out, int out_size, void* d_ws, size_t ws_size,
                              hipStream_t stream) {
    const float* x     = (const float*)d_in[0];
    const float* ew    = (const float*)d_in[1];
    const float* W     = (const float*)d_in[2];
    const float* gamma = (const float*)d_in[3];
    const float* beta  = (const float*)d_in[4];
    const float* mean  = (const float*)d_in[5];
    const float* var   = (const float*)d_in[6];
    const float* fc1_w = (const float*)d_in[7];
    const float* fc1_b = (const float*)d_in[8];
    const float* fc2_w = (const float*)d_in[9];
    const float* fc2_b = (const float*)d_in[10];
    const int*   ei    = (const int*)d_in[11];
    float* out = (float*)d_out;

    // ws layout (4B elems): partial(1250*64=80000) | counts(NPAD) | off(NPAD)
    //   | cursor(NPAD) | bsum(256) | ep(int2 x E) | rres(NH)   ~ 20 MB
    float* partial = (float*)d_ws;
    int*   counts  = (int*)d_ws + 80000;
    int*   off     = counts + NPAD;
    int*   cursor  = off + NPAD;
    int*   bsum    = cursor + NPAD;
    int2*  ep      = (int2*)(bsum + 256);       // 8B-aligned
    float* rres    = (float*)(ep + E_EDGES);
    (void)ws_size; (void)in_sizes; (void)n_in; (void)out_size;

    {   // zero counts only (partial fully overwritten by fc1 every call)
        int n4 = NPAD / 4;
        zero_kernel<<<(n4 + 255) / 256, 256, 0, stream>>>((float4*)counts, n4);
    }
    hist_kernel  <<<(E_EDGES / 2 + 255) / 256, 256, 0, stream>>>(ei, counts);
    scan1_kernel <<<196, 256, 0, stream>>>(counts, bsum);
    scan23_kernel<<<196, 256, 0, stream>>>(counts, bsum, off, cursor);
    place_kernel <<<(E_EDGES / 2 + 255) / 256, 256, 0, stream>>>(ei, ew, cursor, ep);
    gather_kernel<<<N_NODES / 8, 256, 0, stream>>>(x, gamma, beta, mean, var,
                                                   off, ep, W, rres);
    fc1_kernel <<<NBLK, 256, 0, stream>>>(rres, fc1_w, partial);
    reduce_head_kernel<<<1, 1024, 0, stream>>>(partial, fc1_b, fc2_w, fc2_b, out);
}

// Round 5
// 745.263 us; speedup vs baseline: 1.2391x; 1.1039x over previous
//
#include <hip/hip_runtime.h>

constexpr int N_NODES = 50000;
constexpr int E_EDGES = 1600000;
constexpr int NH      = N_NODES * 32;   // 1,600,000
constexpr float BN_EPS = 1e-5f;
constexpr int NBLK    = 1250;           // contract+fc1 blocks (40 nodes each)
constexpr int CNT_PAD = 50016;

// ---------------------------------------------------------------- zero scratch
__global__ void zero_kernel(float4* __restrict__ p, int n4) {
    int i = blockIdx.x * blockDim.x + threadIdx.x;
    if (i < n4) p[i] = make_float4(0.f, 0.f, 0.f, 0.f);
}

// ---------------------------------------------------------------- scatter:
// agg[dst][c] += ew * (BN x)[src][c]  via one coalesced 128B-row atomic per
// edge-half; cnt_self[n] counts self-loop edges (k=0 term = cnt * x_bn[n]).
// Wave = 2 edges x 32 channels. Edge metadata via wave-uniform broadcast
// int2/float2 loads of the sequential ei/ew arrays (1 transaction each).
// No CSR, no ep buffer, no scan, no place.
__global__ void scatter_kernel(const float* __restrict__ x,
                               const float* __restrict__ gamma,
                               const float* __restrict__ beta,
                               const float* __restrict__ mean,
                               const float* __restrict__ var,
                               const int*   __restrict__ ei,
                               const float* __restrict__ ew,
                               float* __restrict__ agg,
                               int*   __restrict__ cnt_self) {
    int tid  = threadIdx.x;
    int lane = tid & 63;
    int c    = lane & 31;                   // channel
    int half = lane >> 5;                   // which edge of the pair
    int wid  = (blockIdx.x << 2) + (tid >> 6);   // 50000 waves, 32 edges each

    float sc = gamma[c] * rsqrtf(var[c] + BN_EPS);
    float sh = beta[c] - mean[c] * sc;

    // wave-uniform edge base -> scalar-load-eligible addresses
    int ebase = __builtin_amdgcn_readfirstlane(wid << 5);
    const int2*   sp = (const int2*)(ei + ebase);             // src pairs
    const int2*   dp = (const int2*)(ei + E_EDGES + ebase);   // dst pairs
    const float2* wp = (const float2*)(ew + ebase);

#pragma unroll
    for (int k = 0; k < 16; k++) {          // 16 pairs = 32 edges
        int2   s2 = sp[k];                  // broadcast: all 64 lanes same addr
        int2   d2 = dp[k];
        float2 w2 = wp[k];
        int   src = half ? s2.y : s2.x;
        int   dst = half ? d2.y : d2.x;
        float w   = half ? w2.y : w2.x;
        float vv  = fmaf(x[src * 32 + c], sc, sh);
        atomicAdd(&agg[dst * 32 + c], w * vv);      // coalesced 128B row RMW
        if (src == dst && c == 0) atomicAdd(&cnt_self[dst], 1);  // ~32 total
    }
}

// ---------------------------------------------------------------- contract + fc1:
// phase A: per node r = relu(agg[n]*Wsum + cnt_self[n]*x_bn[n]*W0) -> LDS
//          (trivial now -- no edge loop, so 1250 blocks lose no TLP)
// phase B: fc1 chunk [64 rows x 1280 cols], coalesced 1KB bursts (the
//          pattern that round-3's per-lane-row fusion broke -- preserved here)
__global__ void cfc1_kernel(const float* __restrict__ x,
                            const float* __restrict__ gamma,
                            const float* __restrict__ beta,
                            const float* __restrict__ mean,
                            const float* __restrict__ var,
                            const float* __restrict__ agg,
                            const int*   __restrict__ cnt_self,
                            const float* __restrict__ W,
                            const float* __restrict__ fc1_w,
                            float* __restrict__ partial) {
    __shared__ float2 s_wp[1024];           // {Wsum, W0} packed per (cc, h)
    __shared__ float2 s_a[4][2][32];        // per wave, per half: {a, a0}
    __shared__ float4 s_r[320];             // 40 nodes x 32 ch relu'd results
    int tid = threadIdx.x;
    for (int idx = tid; idx < 1024; idx += 256)
        s_wp[idx] = make_float2(W[1024 + idx] + W[2048 + idx], W[idx]);
    __syncthreads();

    int lane = tid & 63, c = lane & 31, half = lane >> 5, wslot = tid >> 6;
    float sc = gamma[c] * rsqrtf(var[c] + BN_EPS);
    float sh = beta[c] - mean[c] * sc;
    int   nb0 = blockIdx.x * 40 + wslot * 10;   // wave owns 10 nodes (5 pairs)
    float* s_rf = (float*)s_r;

#pragma unroll
    for (int i = 0; i < 5; i++) {
        int n = nb0 + 2 * i + half;
        float a  = agg[n * 32 + c];             // coalesced 128B per half
        int   cs = cnt_self[n];                 // broadcast
        float a0 = cs ? (float)cs * fmaf(x[n * 32 + c], sc, sh) : 0.f;
        __builtin_amdgcn_wave_barrier();
        s_a[wslot][half][c] = make_float2(a, a0);
        __threadfence_block();                  // drain ds_write
        __builtin_amdgcn_wave_barrier();
        float r = 0.f;
#pragma unroll
        for (int cc = 0; cc < 32; cc++) {
            float2 ap = s_a[wslot][half][cc];   // broadcast per half
            float2 wv = s_wp[cc * 32 + c];
            r = fmaf(ap.x, wv.x, r);
            r = fmaf(ap.y, wv.y, r);
        }
        s_rf[(wslot * 10 + 2 * i + half) * 32 + c] = fmaxf(r, 0.f);
        __builtin_amdgcn_wave_barrier();
    }
    __syncthreads();

    // ---- phase B: fc1, 16 rows/wave, 5 float4 k-iters, 1KB bursts
    int wave = tid >> 6;
    size_t ib = (size_t)blockIdx.x * 1280;
    int jbase = wave * 16;
    float* pout = partial + blockIdx.x * 64;
    for (int jj = 0; jj < 16; jj += 2) {
        const float4* wa = (const float4*)(fc1_w + (size_t)(jbase + jj    ) * NH + ib);
        const float4* wb = (const float4*)(fc1_w + (size_t)(jbase + jj + 1) * NH + ib);
        float a0 = 0.f, a1 = 0.f;
#pragma unroll
        for (int k = 0; k < 5; k++) {
            float4 rv = s_r[lane + k * 64];
            float4 x0 = wa[lane + k * 64];
            float4 x1 = wb[lane + k * 64];
            a0 = fmaf(rv.x, x0.x, a0); a0 = fmaf(rv.y, x0.y, a0);
            a0 = fmaf(rv.z, x0.z, a0); a0 = fmaf(rv.w, x0.w, a0);
            a1 = fmaf(rv.x, x1.x, a1); a1 = fmaf(rv.y, x1.y, a1);
            a1 = fmaf(rv.z, x1.z, a1); a1 = fmaf(rv.w, x1.w, a1);
        }
#pragma unroll
        for (int o = 32; o > 0; o >>= 1) {
            a0 += __shfl_down(a0, o);
            a1 += __shfl_down(a1, o);
        }
        if (lane == 0) {
            pout[jbase + jj    ] = a0;   // plain store, distinct per block
            pout[jbase + jj + 1] = a1;
        }
    }
}

// ---------------------------------------------------------------- reduce + head
__global__ void reduce_head_kernel(const float* __restrict__ partial,
                                   const float* __restrict__ fc1_b,
                                   const float* __restrict__ fc2_w,
                                   const float* __restrict__ fc2_b,
                                   float* __restrict__ out) {
    __shared__ float red[1024];
    int t = threadIdx.x;
    int j = t & 63, s = t >> 6;          // 16 slices over 1250 blocks
    float a = 0.f;
    for (int b = s; b < NBLK; b += 16) a += partial[b * 64 + j];  // coalesced
    red[t] = a;
    __syncthreads();
    if (s == 0) {
        float h = fc1_b[j];
#pragma unroll
        for (int q = 0; q < 16; q++) h += red[q * 64 + j];
        h = fmaxf(h, 0.f);
#pragma unroll
        for (int k = 0; k < 2; k++) {
            float p = h * fc2_w[k * 64 + j];
#pragma unroll
            for (int o = 32; o > 0; o >>= 1) p += __shfl_down(p, o);
            if (j == 0) out[k] = p + fc2_b[k];
        }
    }
}

// ---------------------------------------------------------------- launch
extern "C" void kernel_launch(void* const* d_in, const int* in_sizes, int n_in,
                              void* d_out, int out_size, void* d_ws, size_t ws_size,
                              hipStream_t stream) {
    const float* x     = (const float*)d_in[0];
    const float* ew    = (const float*)d_in[1];
    const float* W     = (const float*)d_in[2];
    const float* gamma = (const float*)d_in[3];
    const float* beta  = (const float*)d_in[4];
    const float* mean  = (const float*)d_in[5];
    const float* var   = (const float*)d_in[6];
    const float* fc1_w = (const float*)d_in[7];
    const float* fc1_b = (const float*)d_in[8];
    const float* fc2_w = (const float*)d_in[9];
    const float* fc2_b = (const float*)d_in[10];
    const int*   ei    = (const int*)d_in[11];
    float* out = (float*)d_out;

    // ws layout (4B elems): agg(1,600,000) | cnt_self(50016) | partial(80000)
    //   total ~6.9 MB; agg+cnt_self zeroed each call (ws is poisoned)
    float* agg      = (float*)d_ws;
    int*   cnt_self = (int*)d_ws + NH;
    float* partial  = (float*)d_ws + NH + CNT_PAD;
    (void)ws_size; (void)in_sizes; (void)n_in; (void)out_size;

    {   // zero agg + cnt_self contiguously: (1600000+50016)/4 = 412504 float4
        int n4 = (NH + CNT_PAD) / 4;
        zero_kernel<<<(n4 + 255) / 256, 256, 0, stream>>>((float4*)d_ws, n4);
    }
    scatter_kernel<<<12500, 256, 0, stream>>>(x, gamma, beta, mean, var,
                                              ei, ew, agg, cnt_self);
    cfc1_kernel<<<NBLK, 256, 0, stream>>>(x, gamma, beta, mean, var,
                                          agg, cnt_self, W, fc1_w, partial);
    reduce_head_kernel<<<1, 1024, 0, stream>>>(partial, fc1_b, fc2_w, fc2_b, out);
}